// Round 9
// baseline (86.011 us; speedup 1.0000x reference)
//
#include <hip/hip_runtime.h>
#include <stdint.h>

// ---- problem constants ----
#define T_TOK 2048
#define H_DIM 1024
#define ID    512    // I
#define E_NUM 8
#define NPAIR 4096   // T_TOK * top_k(2)
#define BM    64
#define MAXTILES 72  // sum ceil(cnt_e/64) <= 64 + 7

typedef _Float16 half_t;
typedef _Float16 f16x8 __attribute__((ext_vector_type(8)));
typedef _Float16 f16x4 __attribute__((ext_vector_type(4)));
typedef float    f32x4 __attribute__((ext_vector_type(4)));

// ---- workspace layout (bytes) ----
#define XB_OFF    ((size_t)0)               // f16 [2048][1024]    4 MiB
#define WGU_OFF   ((size_t)(4u << 20))      // f16 [8][1024][1024] (f-major, k=h contig) 16 MiB
#define WDN_OFF   ((size_t)(20u << 20))     // f16 [8][1024][512]  (h-major, k=i contig)  8 MiB
#define INTER_OFF ((size_t)(28u << 20))     // f16 [4096][512]     4 MiB
#define META_OFF  ((size_t)(32u << 20))     // ints
#define PAIRW_OFF ((size_t)((32u << 20) + 32768))
// meta: [0]=ntiles, [8..80) tile_e, [88..160) tile_row0, [168..240) tile_end,
//       [256..256+4096) pair_token

__device__ __forceinline__ void gload_lds16(const void* g, void* l) {
    __builtin_amdgcn_global_load_lds(
        (const __attribute__((address_space(1))) unsigned int*)g,
        (__attribute__((address_space(3))) unsigned int*)l,
        16, 0, 0);
}

// 64x64 transpose-convert tile: reads in[r0+r][c0+c] (row stride 1024, f32),
// writes out[(c0+c)*out_stride + r0 + r] (f16). smem >= 64*65*4 bytes.
template <int NT>
__device__ __forceinline__ void cvt_tile64(const float* __restrict__ in,
                                           half_t* __restrict__ out,
                                           int r0, int c0, int out_stride,
                                           char* smem) {
    float (*tile)[65] = (float(*)[65])smem;
    int tid = threadIdx.x;
#pragma unroll
    for (int it = 0; it < 1024 / NT; it++) {
        int idx = tid + it * NT;
        int r = idx >> 4, c4 = (idx & 15) * 4;
        float4 v = *(const float4*)(in + (size_t)(r0 + r) * 1024 + c0 + c4);
        tile[r][c4] = v.x; tile[r][c4 + 1] = v.y; tile[r][c4 + 2] = v.z; tile[r][c4 + 3] = v.w;
    }
    __syncthreads();
#pragma unroll
    for (int it = 0; it < 1024 / NT; it++) {
        int idx = tid + it * NT;
        int oc = idx >> 4, r4 = (idx & 15) * 4;
        f16x4 o;
        o[0] = (half_t)tile[r4][oc];
        o[1] = (half_t)tile[r4 + 1][oc];
        o[2] = (half_t)tile[r4 + 2][oc];
        o[3] = (half_t)tile[r4 + 3][oc];
        *(f16x4*)(out + (size_t)(c0 + oc) * out_stride + r0 + r4) = o;
    }
}

// ---- fused prep: cvt x->f16 | route | cvt gate_up weights ----
// grid: [0,1024) cvt_x, [1024] route, [1025, 1025+2048) cvt_wgu
__global__ __launch_bounds__(256) void k_prep(const float* __restrict__ x,
                                              const int* __restrict__ ridx,
                                              const float* __restrict__ rw,
                                              const float* __restrict__ wgu,
                                              half_t* __restrict__ xb,
                                              half_t* __restrict__ wguT,
                                              int* __restrict__ meta,
                                              float* __restrict__ pair_w) {
    __shared__ char smem[16704];
    int b = blockIdx.x, tid = threadIdx.x;
    if (b < 1024) {
        int g = b * 256 + tid;
        size_t b0 = (size_t)g * 8;
        float4 v0 = *(const float4*)(x + b0);
        float4 v1 = *(const float4*)(x + b0 + 4);
        f16x8 o;
        o[0] = (half_t)v0.x; o[1] = (half_t)v0.y; o[2] = (half_t)v0.z; o[3] = (half_t)v0.w;
        o[4] = (half_t)v1.x; o[5] = (half_t)v1.y; o[6] = (half_t)v1.z; o[7] = (half_t)v1.w;
        *(f16x8*)(xb + b0) = o;
    } else if (b == 1024) {
        __shared__ int cnt[E_NUM], cur[E_NUM], base[E_NUM];
        if (tid < E_NUM) { cnt[tid] = 0; cur[tid] = 0; }
        __syncthreads();
        for (int i = tid; i < NPAIR; i += 256) atomicAdd(&cnt[ridx[i]], 1);
        __syncthreads();
        if (tid == 0) {
            int acc = 0, nt = 0;
            for (int e = 0; e < E_NUM; e++) {
                base[e] = acc;
                for (int r = 0; r < cnt[e]; r += BM) {
                    meta[8 + nt] = e; meta[88 + nt] = acc + r; meta[168 + nt] = acc + cnt[e]; nt++;
                }
                acc += cnt[e];
            }
            meta[0] = nt;
        }
        __syncthreads();
        for (int i = tid; i < NPAIR; i += 256) {
            int e = ridx[i];
            int pos = atomicAdd(&cur[e], 1);
            int slot = base[e] + pos;
            meta[256 + slot] = i >> 1;   // pair_token
            pair_w[slot] = rw[i];
        }
    } else {
        int t = b - 1025;                 // [0, 2048): gate_up expert tiles
        int e = t >> 8, rem = t & 255;
        int h0 = (rem >> 4) * 64, f0 = (rem & 15) * 64;
        cvt_tile64<256>(wgu + (size_t)e * 1024 * 1024, wguT + (size_t)e * 1024 * 1024,
                        h0, f0, 1024, smem);
    }
}

// 2-wave GEMM, block tile 64x128, per-wave 64x64 (acc[4][4]).
// 3-deep LDS pipeline, counted s_waitcnt vmcnt(12) + raw s_barrier (never drain in loop).
// MODE 0: A = xb gathered (K=1024), B = wguT cols remapped so wave frags {0,1}=gate,
//         {2,3}=up; epilogue = in-register SwiGLU -> inter f16.
//         aux blocks: [576,1600) cvt down-proj; [1600,2112) zero d_out.
// MODE 1: A = inter (K=512), B = wdnT; epilogue = agent-scope atomicAdd(out*pair_w).
template <int MODE>
__global__ __launch_bounds__(128) void k_gemm(const int* __restrict__ meta,
                                              const half_t* __restrict__ amat,
                                              const half_t* __restrict__ wT,
                                              const float* __restrict__ pair_w,
                                              void* __restrict__ outp,
                                              const float* __restrict__ aux_in,
                                              half_t* __restrict__ aux_out,
                                              float4* __restrict__ zero_out) {
    constexpr int KSZ = MODE ? ID : H_DIM;
    constexpr int NKT = KSZ / 64;
    // 3 bufs x (A 8K + B 16K) = 72 KiB; cvt tile aliases
    __shared__ __align__(16) char smem[73728];

    int d = blockIdx.x;
    if (MODE == 0 && d >= 576) {
        int d2 = d - 576;
        if (d2 < 1024) {           // cvt down-proj: in [e][512 i][1024 h] -> out [e][h][i]
            int e = d2 >> 7, rem = d2 & 127;
            int h0 = (rem >> 3) * 64, i0 = (rem & 7) * 64;
            cvt_tile64<128>(aux_in + (size_t)e * ID * 1024, aux_out + (size_t)e * 1024 * ID,
                            i0, h0, ID, smem);
        } else {                   // zero d_out: 512 blocks * 16 KiB = 8 MiB
            int z = d2 - 1024;
            float4 zv = make_float4(0.f, 0.f, 0.f, 0.f);
            float4* p = zero_out + (size_t)z * 1024 + threadIdx.x;
#pragma unroll
            for (int k = 0; k < 8; k++) p[k * 128] = zv;
        }
        return;
    }

    int l = (d & 7) * MAXTILES + (d >> 3);    // XCD c owns l in [c*72, c*72+72)
    int bx = l >> 3, by = l & 7;
    int nt = meta[0];
    if (bx >= nt) return;
    int e = meta[8 + bx], row0 = meta[88 + bx], rend = meta[168 + bx];
    const int* pair_token = meta + 256;

    int tid = threadIdx.x, lane = tid & 63, wid = tid >> 6;   // wid 0/1

    // A staging: 8 chunks of 1KB (8 rows x 64 halves), thread's chunks gch = wid*4+i
    const half_t* asrc[4]; int aoff[4];
#pragma unroll
    for (int i = 0; i < 4; i++) {
        int gch = wid * 4 + i;
        int r = gch * 8 + (lane >> 3), pc = lane & 7, lc = pc ^ (r & 7);
        int pr = row0 + r; if (pr > NPAIR - 1) pr = NPAIR - 1;
        const half_t* rowp = (MODE == 0) ? amat + (size_t)pair_token[pr] * KSZ
                                         : amat + (size_t)pr * KSZ;
        asrc[i] = rowp + lc * 8;
        aoff[i] = gch * 1024 + lane * 16;
    }
    // B staging: 16 chunks; B-row br -> physcol per MODE
    const half_t* wbase = wT + (size_t)e * 1024 * KSZ;
    const half_t* bsrc[8]; int boff[8];
#pragma unroll
    for (int i = 0; i < 8; i++) {
        int gch = wid * 8 + i;
        int br = gch * 8 + (lane >> 3), pc = lane & 7, lc = pc ^ (br & 7);
        int physcol;
        if (MODE == 0) {
            int w = br >> 6, f = (br >> 4) & 3, ll = br & 15;
            physcol = by * 64 + w * 32 + (f & 1) * 16 + ll + ((f & 2) ? 512 : 0);
        } else {
            physcol = by * 128 + br;
        }
        bsrc[i] = wbase + (size_t)physcol * KSZ + lc * 8;
        boff[i] = 8192 + gch * 1024 + lane * 16;
    }

    auto stage = [&](int bufb, int kt) {
        char* base = smem + bufb * 24576;
#pragma unroll
        for (int i = 0; i < 4; i++) gload_lds16(asrc[i] + kt * 64, base + aoff[i]);
#pragma unroll
        for (int i = 0; i < 8; i++) gload_lds16(bsrc[i] + kt * 64, base + boff[i]);
    };

    f32x4 acc[4][4] = {};

    auto compute = [&](int bufb) {
        const char* Ab = smem + bufb * 24576;
        const char* Bb = Ab + 8192;
#pragma unroll
        for (int ks = 0; ks < 2; ks++) {
            f16x8 af[4], bf[4];
#pragma unroll
            for (int f = 0; f < 4; f++) {
                int ar = f * 16 + (lane & 15);
                int apc = (ks * 4 + (lane >> 4)) ^ (ar & 7);
                af[f] = *(const f16x8*)(Ab + ar * 128 + apc * 16);
                int br = wid * 64 + f * 16 + (lane & 15);
                int bpc = (ks * 4 + (lane >> 4)) ^ (br & 7);
                bf[f] = *(const f16x8*)(Bb + br * 128 + bpc * 16);
            }
#pragma unroll
            for (int fm = 0; fm < 4; fm++)
#pragma unroll
                for (int fn = 0; fn < 4; fn++)
                    acc[fm][fn] = __builtin_amdgcn_mfma_f32_16x16x32_f16(af[fm], bf[fn], acc[fm][fn], 0, 0, 0);
        }
    };

    stage(0, 0);
    stage(1, 1);
    int cur = 0, stg = 2;
    for (int kt = 0; kt < NKT - 2; kt++) {
        asm volatile("s_waitcnt vmcnt(12)" ::: "memory");   // stage kt done; kt+1 in flight
        __builtin_amdgcn_s_barrier();
        stage(stg, kt + 2);
        compute(cur);
        cur = cur == 2 ? 0 : cur + 1;
        stg = stg == 2 ? 0 : stg + 1;
    }
    asm volatile("s_waitcnt vmcnt(12)" ::: "memory");
    __builtin_amdgcn_s_barrier();
    compute(cur);
    cur = cur == 2 ? 0 : cur + 1;
    asm volatile("s_waitcnt vmcnt(0)" ::: "memory");
    __builtin_amdgcn_s_barrier();
    compute(cur);

    // C/D layout: col = lane&15, row = (lane>>4)*4 + j
    if (MODE == 0) {
        half_t* inter = (half_t*)outp;
#pragma unroll
        for (int fm = 0; fm < 4; fm++) {
            int rbase = fm * 16 + (lane >> 4) * 4;
#pragma unroll
            for (int j = 0; j < 4; j++) {
                int packed = row0 + rbase + j;
                if (packed < rend) {
                    int col = by * 64 + wid * 32 + (lane & 15);
                    float g0 = acc[fm][0][j], u0 = acc[fm][2][j];
                    float g1 = acc[fm][1][j], u1 = acc[fm][3][j];
                    half_t* rowp = inter + (size_t)packed * ID;
                    rowp[col]      = (half_t)(g0 / (1.0f + __expf(-g0)) * u0);
                    rowp[col + 16] = (half_t)(g1 / (1.0f + __expf(-g1)) * u1);
                }
            }
        }
    } else {
        float* out = (float*)outp;
#pragma unroll
        for (int fm = 0; fm < 4; fm++) {
            int rbase = fm * 16 + (lane >> 4) * 4;
#pragma unroll
            for (int j = 0; j < 4; j++) {
                int packed = row0 + rbase + j;
                if (packed < rend) {
                    int t = pair_token[packed];
                    float pw = pair_w[packed];
#pragma unroll
                    for (int fn = 0; fn < 4; fn++) {
                        int col = by * 128 + wid * 64 + fn * 16 + (lane & 15);
                        // agent-scope f32 atomic: coherent across XCDs
                        __hip_atomic_fetch_add(&out[(size_t)t * H_DIM + col],
                                               acc[fm][fn][j] * pw,
                                               __ATOMIC_RELAXED,
                                               __HIP_MEMORY_SCOPE_AGENT);
                    }
                }
            }
        }
    }
}

extern "C" void kernel_launch(void* const* d_in, const int* in_sizes, int n_in,
                              void* d_out, int out_size, void* d_ws, size_t ws_size,
                              hipStream_t stream) {
    const float* x    = (const float*)d_in[0];
    const int*   ridx = (const int*)d_in[1];
    const float* rw   = (const float*)d_in[2];
    const float* wgu  = (const float*)d_in[3];
    const float* wdn  = (const float*)d_in[4];
    float* out = (float*)d_out;

    char* ws = (char*)d_ws;
    half_t* xb    = (half_t*)(ws + XB_OFF);
    half_t* wguT  = (half_t*)(ws + WGU_OFF);
    half_t* wdnT  = (half_t*)(ws + WDN_OFF);
    half_t* inter = (half_t*)(ws + INTER_OFF);
    int*    meta  = (int*)(ws + META_OFF);
    float*  pair_w = (float*)(ws + PAIRW_OFF);

    // L1: cvt_x (1024) | route (1) | cvt gate_up (2048)
    k_prep<<<3073, 256, 0, stream>>>(x, ridx, rw, wgu, xb, wguT, meta, pair_w);
    // L2: GEMM1 (576) | cvt down (1024) | zero out (512)
    k_gemm<0><<<2112, 128, 0, stream>>>(meta, xb, wguT, pair_w, inter, wdn, wdnT, (float4*)out);
    // L3: GEMM2 (576)
    k_gemm<1><<<576, 128, 0, stream>>>(meta, inter, wdnT, pair_w, out, nullptr, nullptr, nullptr);
}

// Round 11
// 69.141 us; speedup vs baseline: 1.2440x; 1.2440x over previous
//
#include <hip/hip_runtime.h>
#include <stdint.h>

// ---- problem constants ----
#define T_TOK 2048
#define H_DIM 1024
#define ID    512    // I
#define E_NUM 8
#define NPAIR 4096   // T_TOK * top_k(2)
#define BM    128
#define MAXTILES 40  // sum ceil(cnt_e/128) <= 32 + 7

typedef _Float16 half_t;
typedef _Float16 f16x8 __attribute__((ext_vector_type(8)));
typedef _Float16 f16x4 __attribute__((ext_vector_type(4)));
typedef float    f32x4 __attribute__((ext_vector_type(4)));

// ---- workspace layout (bytes) ----
#define XB_OFF    ((size_t)0)               // f16 [2048][1024]    4 MiB
#define WGU_OFF   ((size_t)(4u << 20))      // f16 [8][1024][1024] (f-major, k=h contig) 16 MiB
#define WDN_OFF   ((size_t)(20u << 20))     // f16 [8][1024][512]  (h-major, k=i contig)  8 MiB
#define INTER_OFF ((size_t)(28u << 20))     // f16 [4096][512]     4 MiB
#define META_OFF  ((size_t)(32u << 20))     // ints
#define PAIRW_OFF ((size_t)((32u << 20) + 32768))
// meta: [0]=ntiles, [8..48) tile_e, [88..128) tile_row0, [168..208) tile_end,
//       [256..256+4096) pair_token

__device__ __forceinline__ void gload_lds16(const void* g, void* l) {
    __builtin_amdgcn_global_load_lds(
        (const __attribute__((address_space(1))) unsigned int*)g,
        (__attribute__((address_space(3))) unsigned int*)l,
        16, 0, 0);
}

// pipeline barrier: wave's own vmcnt wait BEFORE the barrier (others' loads are
// covered by their waits + the barrier); sched_barrier(0) AFTER it pins the
// following ds_read/global_load_lds from being hoisted into the pre-barrier gap
// (rule #18 class hazard: s_barrier is not a compiler memory fence -> R10's race).
#define PIPE_BARRIER(N)                                          \
    {                                                            \
        asm volatile("s_waitcnt vmcnt(" #N ")" ::: "memory");    \
        __builtin_amdgcn_s_barrier();                            \
        __builtin_amdgcn_sched_barrier(0);                       \
    }

// 64x64 transpose-convert tile: reads in[r0+r][c0+c] (row stride 1024, f32),
// writes out[(c0+c)*out_stride + r0 + r] (f16). smem >= 64*65*4 bytes.
template <int NT>
__device__ __forceinline__ void cvt_tile64(const float* __restrict__ in,
                                           half_t* __restrict__ out,
                                           int r0, int c0, int out_stride,
                                           char* smem) {
    float (*tile)[65] = (float(*)[65])smem;
    int tid = threadIdx.x;
#pragma unroll
    for (int it = 0; it < 1024 / NT; it++) {
        int idx = tid + it * NT;
        int r = idx >> 4, c4 = (idx & 15) * 4;
        float4 v = *(const float4*)(in + (size_t)(r0 + r) * 1024 + c0 + c4);
        tile[r][c4] = v.x; tile[r][c4 + 1] = v.y; tile[r][c4 + 2] = v.z; tile[r][c4 + 3] = v.w;
    }
    __syncthreads();
#pragma unroll
    for (int it = 0; it < 1024 / NT; it++) {
        int idx = tid + it * NT;
        int oc = idx >> 4, r4 = (idx & 15) * 4;
        f16x4 o;
        o[0] = (half_t)tile[r4][oc];
        o[1] = (half_t)tile[r4 + 1][oc];
        o[2] = (half_t)tile[r4 + 2][oc];
        o[3] = (half_t)tile[r4 + 3][oc];
        *(f16x4*)(out + (size_t)(c0 + oc) * out_stride + r0 + r4) = o;
    }
}

// ---- fused prep: cvt x->f16 | route | cvt gate_up weights ----
// grid: [0,1024) cvt_x, [1024] route, [1025, 1025+2048) cvt_wgu
__global__ __launch_bounds__(256) void k_prep(const float* __restrict__ x,
                                              const int* __restrict__ ridx,
                                              const float* __restrict__ rw,
                                              const float* __restrict__ wgu,
                                              half_t* __restrict__ xb,
                                              half_t* __restrict__ wguT,
                                              int* __restrict__ meta,
                                              float* __restrict__ pair_w) {
    __shared__ char smem[16704];
    int b = blockIdx.x, tid = threadIdx.x;
    if (b < 1024) {
        int g = b * 256 + tid;
        size_t b0 = (size_t)g * 8;
        float4 v0 = *(const float4*)(x + b0);
        float4 v1 = *(const float4*)(x + b0 + 4);
        f16x8 o;
        o[0] = (half_t)v0.x; o[1] = (half_t)v0.y; o[2] = (half_t)v0.z; o[3] = (half_t)v0.w;
        o[4] = (half_t)v1.x; o[5] = (half_t)v1.y; o[6] = (half_t)v1.z; o[7] = (half_t)v1.w;
        *(f16x8*)(xb + b0) = o;
    } else if (b == 1024) {
        __shared__ int cnt[E_NUM], cur[E_NUM], base[E_NUM];
        if (tid < E_NUM) { cnt[tid] = 0; cur[tid] = 0; }
        __syncthreads();
        for (int i = tid; i < NPAIR; i += 256) atomicAdd(&cnt[ridx[i]], 1);
        __syncthreads();
        if (tid == 0) {
            int acc = 0, nt = 0;
            for (int e = 0; e < E_NUM; e++) {
                base[e] = acc;
                for (int r = 0; r < cnt[e]; r += BM) {
                    meta[8 + nt] = e; meta[88 + nt] = acc + r; meta[168 + nt] = acc + cnt[e]; nt++;
                }
                acc += cnt[e];
            }
            meta[0] = nt;
        }
        __syncthreads();
        for (int i = tid; i < NPAIR; i += 256) {
            int e = ridx[i];
            int pos = atomicAdd(&cur[e], 1);
            int slot = base[e] + pos;
            meta[256 + slot] = i >> 1;   // pair_token
            pair_w[slot] = rw[i];
        }
    } else {
        int t = b - 1025;                 // [0, 2048): gate_up expert tiles
        int e = t >> 8, rem = t & 255;
        int h0 = (rem >> 4) * 64, f0 = (rem & 15) * 64;
        cvt_tile64<256>(wgu + (size_t)e * 1024 * 1024, wguT + (size_t)e * 1024 * 1024,
                        h0, f0, 1024, smem);
    }
}

// 4-wave GEMM (2x2 wave grid), block tile 128x128, BK=32, per-wave 64x64 (acc[4][4]).
// 3-deep LDS pipeline (3 x 16 KiB = 48 KiB -> 3 blocks/CU, 12 waves/CU), counted
// s_waitcnt vmcnt(4) + raw s_barrier + sched_barrier(0): one stage always in flight.
// LDS rows are 64B; swizzle 16B-slot with ((row>>2)&3) -> <=2-way read conflicts.
// MODE 0: A = xb gathered (K=1024), B = wguT cols remapped (frags {0,1}=gate, {2,3}=up);
//         epilogue = in-register SwiGLU -> inter f16.
//         aux blocks: [320,1344) cvt down-proj; [1344,1856) zero d_out.
// MODE 1: A = inter (K=512), B = wdnT; epilogue = agent-scope atomicAdd(out*pair_w).
template <int MODE>
__global__ __launch_bounds__(256) void k_gemm(const int* __restrict__ meta,
                                              const half_t* __restrict__ amat,
                                              const half_t* __restrict__ wT,
                                              const float* __restrict__ pair_w,
                                              void* __restrict__ outp,
                                              const float* __restrict__ aux_in,
                                              half_t* __restrict__ aux_out,
                                              float4* __restrict__ zero_out) {
    constexpr int KSZ = MODE ? ID : H_DIM;
    constexpr int NKT = KSZ / 32;
    __shared__ __align__(16) char smem[49152];   // 3 bufs x (A 8K | B 8K); cvt aliases

    int d = blockIdx.x;
    if (MODE == 0 && d >= 320) {
        int d2 = d - 320;
        if (d2 < 1024) {           // cvt down-proj: in [e][512 i][1024 h] -> out [e][h][i]
            int e = d2 >> 7, rem = d2 & 127;
            int h0 = (rem >> 3) * 64, i0 = (rem & 7) * 64;
            cvt_tile64<256>(aux_in + (size_t)e * ID * 1024, aux_out + (size_t)e * 1024 * ID,
                            i0, h0, ID, smem);
        } else {                   // zero d_out: 512 blocks * 16 KiB = 8 MiB
            int z = d2 - 1024;
            float4 zv = make_float4(0.f, 0.f, 0.f, 0.f);
            float4* p = zero_out + (size_t)z * 1024 + threadIdx.x;
            p[0] = zv; p[256] = zv; p[512] = zv; p[768] = zv;
        }
        return;
    }

    int l = (d & 7) * MAXTILES + (d >> 3);    // XCD c owns l in [c*40, c*40+40)
    int bx = l >> 3, by = l & 7;              // 5 consecutive row-tiles/XCD (~1 expert)
    int nt = meta[0];
    if (bx >= nt) return;
    int e = meta[8 + bx], row0 = meta[88 + bx], rend = meta[168 + bx];
    const int* pair_token = meta + 256;

    int tid = threadIdx.x, lane = tid & 63, wid = tid >> 6;   // 4 waves
    int wm = wid >> 1, wn = wid & 1;

    // ---- staging setup: A tile [128 rows][32 halves], B tile [128 brows][32 halves]
    // chunk = 1 KiB = 64 lanes x 16B; lane in chunk gch: row = gch*16 + (lane>>2),
    // phys 16B-slot = lane&3 holds global k-chunk (lane&3)^((row>>2)&3).
    const half_t* asrc[2]; int aoff[2];
#pragma unroll
    for (int i = 0; i < 2; i++) {
        int gch = wid * 2 + i;
        int r = gch * 16 + (lane >> 2);
        int lc = (lane & 3) ^ ((r >> 2) & 3);
        int pr = row0 + r; if (pr > NPAIR - 1) pr = NPAIR - 1;
        const half_t* rowp = (MODE == 0) ? amat + (size_t)pair_token[pr] * KSZ
                                         : amat + (size_t)pr * KSZ;
        asrc[i] = rowp + lc * 8;
        aoff[i] = gch * 1024;               // wave-uniform LDS base (+lane*16 by HW)
    }
    const half_t* wbase = wT + (size_t)e * 1024 * KSZ;
    const half_t* bsrc[2]; int boff[2];
#pragma unroll
    for (int i = 0; i < 2; i++) {
        int gch = wid * 2 + i;
        int br = gch * 16 + (lane >> 2);
        int lc = (lane & 3) ^ ((br >> 2) & 3);
        int physcol;
        if (MODE == 0) {
            int w = br >> 6, f = (br >> 4) & 3, ll = br & 15;
            physcol = by * 64 + w * 32 + (f & 1) * 16 + ll + ((f & 2) ? 512 : 0);
        } else {
            physcol = by * 128 + br;
        }
        bsrc[i] = wbase + (size_t)physcol * KSZ + lc * 8;
        boff[i] = 8192 + gch * 1024;
    }

    auto stage = [&](int buf, int kt) {
        char* base = smem + buf * 16384;
#pragma unroll
        for (int i = 0; i < 2; i++) gload_lds16(asrc[i] + kt * 32, base + aoff[i]);
#pragma unroll
        for (int i = 0; i < 2; i++) gload_lds16(bsrc[i] + kt * 32, base + boff[i]);
    };

    f32x4 acc[4][4] = {};

    auto compute = [&](int buf) {
        const char* Ab = smem + buf * 16384;
        const char* Bb = Ab + 8192;
        f16x8 af[4], bf[4];
#pragma unroll
        for (int f = 0; f < 4; f++) {
            int ar = wm * 64 + f * 16 + (lane & 15);
            int apc = (lane >> 4) ^ ((ar >> 2) & 3);
            af[f] = *(const f16x8*)(Ab + ar * 64 + apc * 16);
            int br = wn * 64 + f * 16 + (lane & 15);
            int bpc = (lane >> 4) ^ ((br >> 2) & 3);
            bf[f] = *(const f16x8*)(Bb + br * 64 + bpc * 16);
        }
#pragma unroll
        for (int fm = 0; fm < 4; fm++)
#pragma unroll
            for (int fn = 0; fn < 4; fn++)
                acc[fm][fn] = __builtin_amdgcn_mfma_f32_16x16x32_f16(af[fm], bf[fn], acc[fm][fn], 0, 0, 0);
    };

    stage(0, 0);
    stage(1, 1);
    int cur = 0, stg = 2;
    for (int kt = 0; kt < NKT - 2; kt++) {
        PIPE_BARRIER(4);                   // stage kt retired; kt+1 in flight
        stage(stg, kt + 2);
        compute(cur);
        cur = cur == 2 ? 0 : cur + 1;
        stg = stg == 2 ? 0 : stg + 1;
    }
    PIPE_BARRIER(4);
    compute(cur);
    cur = cur == 2 ? 0 : cur + 1;
    PIPE_BARRIER(0);
    compute(cur);

    // C/D layout: col(lane&15) = B-frag row; C row = (lane>>4)*4 + j
    if (MODE == 0) {
        half_t* inter = (half_t*)outp;
#pragma unroll
        for (int fm = 0; fm < 4; fm++) {
            int rbase = wm * 64 + fm * 16 + (lane >> 4) * 4;
#pragma unroll
            for (int j = 0; j < 4; j++) {
                int packed = row0 + rbase + j;
                if (packed < rend) {
                    half_t* rowp = inter + (size_t)packed * ID;
#pragma unroll
                    for (int fn = 0; fn < 2; fn++) {
                        int col = by * 64 + wn * 32 + fn * 16 + (lane & 15);
                        float g = acc[fm][fn][j], u = acc[fm][fn + 2][j];
                        rowp[col] = (half_t)(g / (1.0f + __expf(-g)) * u);
                    }
                }
            }
        }
    } else {
        float* out = (float*)outp;
#pragma unroll
        for (int fm = 0; fm < 4; fm++) {
            int rbase = wm * 64 + fm * 16 + (lane >> 4) * 4;
#pragma unroll
            for (int j = 0; j < 4; j++) {
                int packed = row0 + rbase + j;
                if (packed < rend) {
                    int t = pair_token[packed];
                    float pw = pair_w[packed];
#pragma unroll
                    for (int fn = 0; fn < 4; fn++) {
                        int col = by * 128 + wn * 64 + fn * 16 + (lane & 15);
                        // agent-scope f32 atomic: coherent across XCDs
                        __hip_atomic_fetch_add(&out[(size_t)t * H_DIM + col],
                                               acc[fm][fn][j] * pw,
                                               __ATOMIC_RELAXED,
                                               __HIP_MEMORY_SCOPE_AGENT);
                    }
                }
            }
        }
    }
}

extern "C" void kernel_launch(void* const* d_in, const int* in_sizes, int n_in,
                              void* d_out, int out_size, void* d_ws, size_t ws_size,
                              hipStream_t stream) {
    const float* x    = (const float*)d_in[0];
    const int*   ridx = (const int*)d_in[1];
    const float* rw   = (const float*)d_in[2];
    const float* wgu  = (const float*)d_in[3];
    const float* wdn  = (const float*)d_in[4];
    float* out = (float*)d_out;

    char* ws = (char*)d_ws;
    half_t* xb    = (half_t*)(ws + XB_OFF);
    half_t* wguT  = (half_t*)(ws + WGU_OFF);
    half_t* wdnT  = (half_t*)(ws + WDN_OFF);
    half_t* inter = (half_t*)(ws + INTER_OFF);
    int*    meta  = (int*)(ws + META_OFF);
    float*  pair_w = (float*)(ws + PAIRW_OFF);

    // L1: cvt_x (1024) | route (1) | cvt gate_up (2048)
    k_prep<<<3073, 256, 0, stream>>>(x, ridx, rw, wgu, xb, wguT, meta, pair_w);
    // L2: GEMM1 (320) | cvt down (1024) | zero out (512)
    k_gemm<0><<<1856, 256, 0, stream>>>(meta, xb, wguT, pair_w, inter, wdn, wdnT, (float4*)out);
    // L3: GEMM2 (320)
    k_gemm<1><<<320, 256, 0, stream>>>(meta, inter, wdnT, pair_w, out, nullptr, nullptr, nullptr);
}